// Round 5
// baseline (942.249 us; speedup 1.0000x reference)
//
#include <hip/hip_runtime.h>
#include <hip/hip_cooperative_groups.h>
#include <math.h>

namespace cg = cooperative_groups;

#define HH 512
#define WW 512
#define HWSZ (HH * WW)          // 262144
#define NB 4
#define NPIX (NB * HWSZ)        // 1048576
#define TMAX 16

#define CAP 131072              // dense component capacity (observed n_comp ~70k)
#define NPART 24                // padded partials row (21 used)
#define MB 1024                 // mega-kernel blocks (256 thr, 4 blocks/CU co-resident)
#define SB 1024                 // per-t min-row length (mega path)
// fallback path sizes (round-4, verified)
#define INIT_BLOCKS 1024
#define CBLK 256
#define SBLK 512

struct Scalars {
  double sums[4];               // bce, sum_p, sum_pt, sum_t
  int cnt_t[TMAX + 1];
  int n_comp;
};

__device__ __forceinline__ float pair_loss(float cp, float it, float ctf) {
  const float Nf = (float)NPIX;
  float bce = (Nf * 0.69314718f + cp * 0.62011451f - it) / Nf;  // SP0, SP1-SP0
  float sum_pt = 0.5f * ctf + 0.23105858f * it;                 // S1-0.5
  float sum_p = 0.5f * Nf + 0.23105858f * cp;
  float dice = 1.0f - (2.0f * sum_pt + 1.0f) / (sum_p + ctf + 1.0f);
  return bce + dice;            // always > 0 -> float bits order == value order
}

// ---- union-find helpers ----
// read-only chase (no writes): used where exactness of P[i] contents matters
__device__ __forceinline__ int chaseRO(const int* __restrict__ P, int x) {
  int p = P[x];
  while (p != x) { x = p; p = P[x]; }
  return x;
}
// path-halving find (ECL-CC style; plain stores write ancestors only — benign)
__device__ __forceinline__ int findRootH(int* P, int x) {
  int p = P[x];
  while (p != x) {
    int gp = P[p];
    if (gp == p) return p;
    P[x] = gp;                   // halving: monotone (gp >= p), valid ancestor
    x = gp; p = P[x];
  }
  return x;
}
__device__ void uniteM(int* P, int a, int b) {
  a = findRootH(P, a);
  b = findRootH(P, b);
  for (;;) {
    if (a == b) return;
    if (a > b) { int t = a; a = b; b = t; }     // a < b : link a -> b
    int old = atomicMax(&P[a], b);
    if (old == a) return;
    a = findRootH(P, old);
    b = findRootH(P, b);
  }
}
// fallback (round-4 verified, no halving)
__device__ __forceinline__ int findRootF(const int* __restrict__ P, int x) {
  int p = P[x];
  while (p != x) { x = p; p = P[x]; }
  return x;
}
__device__ void uniteF(int* P, int a, int b) {
  a = findRootF(P, a);
  b = findRootF(P, b);
  for (;;) {
    if (a == b) return;
    if (a > b) { int t = a; a = b; b = t; }
    int old = atomicMax(&P[a], b);
    if (old == a) return;
    a = findRootF(P, old);
    b = findRootF(P, b);
  }
}

// ==================== cooperative mega-kernel ====================
__global__ __launch_bounds__(256, 4) void k_mega(const float* __restrict__ pred,
                                                 const int* __restrict__ tgt,
                                                 int* __restrict__ P,
                                                 int* __restrict__ cnt,
                                                 double* __restrict__ part,
                                                 Scalars* __restrict__ sc,
                                                 int* __restrict__ bcnt,
                                                 int* __restrict__ cntD,
                                                 int* __restrict__ interD,
                                                 unsigned long long* __restrict__ bm,
                                                 float* __restrict__ out) {
  cg::grid_group gg = cg::this_grid();
  const int tid = threadIdx.x;
  const int bid = blockIdx.x;
  const int g = bid * 256 + tid;
  const int lane = tid & 63, wv = tid >> 6;

  __shared__ int hist[TMAX + 1];
  __shared__ double redd[4][4];
  __shared__ double redr[4][21];
  __shared__ int redi[4];
  __shared__ int redp4[4];
  __shared__ int wtot[4];
  __shared__ unsigned long long wmin[4][16];
  __shared__ int s_used[16];
  __shared__ int s_nused;
  __shared__ unsigned long long s_m;
  __shared__ int s_state;

  // ---------- Phase A: init (fg, P, cnt=0, interD=0, partial sums, hist) ----------
  if (tid <= TMAX) hist[tid] = 0;
  __syncthreads();
  {
    int i = g << 2;
    int b = i >> 18;
    int hw = i & (HWSZ - 1);
    const float* pb = pred + ((size_t)(b << 1)) * HWSZ;
    float4 p0 = *(const float4*)(pb + hw);
    float4 p1 = *(const float4*)(pb + HWSZ + hw);
    int4 tv = *(const int4*)(tgt + i);
    int4 lv;
    float s0 = 0.f, s1 = 0.f, s2 = 0.f, s3 = 0.f;
#define ELEM(P0, P1, TV, IDX, LOUT)                              \
    {                                                            \
      bool fg = (P1) > (P0);                                     \
      float logit = fg ? (P1) : 0.0f;                            \
      float tb = ((TV) > 0) ? 1.0f : 0.0f;                       \
      float sp = fmaxf(logit, 0.0f) + log1pf(expf(-fabsf(logit))); \
      s0 += sp - logit * tb;                                     \
      float pr = 1.0f / (1.0f + expf(-logit));                   \
      s1 += pr; s2 += pr * tb; s3 += tb;                         \
      atomicAdd(&hist[TV], 1);                                   \
      LOUT = fg ? (IDX) : -1;                                    \
    }
    ELEM(p0.x, p1.x, tv.x, i + 0, lv.x)
    ELEM(p0.y, p1.y, tv.y, i + 1, lv.y)
    ELEM(p0.z, p1.z, tv.z, i + 2, lv.z)
    ELEM(p0.w, p1.w, tv.w, i + 3, lv.w)
#undef ELEM
    *(int4*)(P + i) = lv;
    *(int4*)(cnt + i) = make_int4(0, 0, 0, 0);
    // zero interD: 8 ints per thread covers CAP*16 = 2M ints
    *(int4*)(interD + ((size_t)g << 3)) = make_int4(0, 0, 0, 0);
    *(int4*)(interD + ((size_t)g << 3) + 4) = make_int4(0, 0, 0, 0);

    for (int o = 32; o > 0; o >>= 1) {
      s0 += __shfl_down(s0, o);
      s1 += __shfl_down(s1, o);
      s2 += __shfl_down(s2, o);
      s3 += __shfl_down(s3, o);
    }
    if (!lane) { redd[wv][0] = s0; redd[wv][1] = s1; redd[wv][2] = s2; redd[wv][3] = s3; }
    __syncthreads();
    double* row = part + (size_t)bid * NPART;
    if (tid <= TMAX) row[4 + tid] = (double)hist[tid];
    if (!tid) {
      row[0] = redd[0][0] + redd[1][0] + redd[2][0] + redd[3][0];
      row[1] = redd[0][1] + redd[1][1] + redd[2][1] + redd[3][1];
      row[2] = redd[0][2] + redd[1][2] + redd[2][2] + redd[3][2];
      row[3] = redd[0][3] + redd[1][3] + redd[2][3] + redd[3][3];
    }
  }
  gg.sync();

  // ---------- Phase B: block0 reduces scalars; all blocks link ----------
  if (bid == 0) {
    double v[21];
#pragma unroll
    for (int j = 0; j < 21; ++j) v[j] = 0.0;
    for (int r = tid; r < MB; r += 256) {
      const double* row = part + (size_t)r * NPART;
#pragma unroll
      for (int j = 0; j < 21; ++j) v[j] += row[j];
    }
#pragma unroll
    for (int o = 32; o > 0; o >>= 1) {
#pragma unroll
      for (int j = 0; j < 21; ++j) v[j] += __shfl_down(v[j], o);
    }
    if (!lane) {
#pragma unroll
      for (int j = 0; j < 21; ++j) redr[wv][j] = v[j];
    }
    __syncthreads();
    if (!tid) {
#pragma unroll
      for (int j = 0; j < 21; ++j) v[j] = redr[0][j] + redr[1][j] + redr[2][j] + redr[3][j];
      sc->sums[0] = v[0]; sc->sums[1] = v[1]; sc->sums[2] = v[2]; sc->sums[3] = v[3];
      for (int j = 0; j <= TMAX; ++j) sc->cnt_t[j] = (int)(v[4 + j] + 0.5);
    }
  }
  {
    int base = bid << 10;
#pragma unroll
    for (int k = 0; k < 4; ++k) {
      int i = base + (k << 8) + tid;
      if (P[i] >= 0) {
        int hw = i & (HWSZ - 1);
        int h = hw >> 9;
        int w = hw & (WW - 1);
        if (w < WW - 1 && P[i + 1] >= 0)  uniteM(P, i, i + 1);
        if (h < HH - 1 && P[i + WW] >= 0) uniteM(P, i, i + WW);
      }
    }
  }
  gg.sync();

  // ---------- Phase C: flatten P in place (owner store = exact root) + count ----------
  {
    int i0 = g << 2;
    int4 pv = *(const int4*)(P + i0);
    int4 rv;
    rv.x = (pv.x < 0) ? -1 : chaseRO(P, pv.x);
    rv.y = (pv.y < 0) ? -1 : chaseRO(P, pv.y);
    rv.z = (pv.z < 0) ? -1 : chaseRO(P, pv.z);
    rv.w = (pv.w < 0) ? -1 : chaseRO(P, pv.w);
    *(int4*)(P + i0) = rv;      // each entry written only by its owner thread
    if (rv.x >= 0) atomicAdd(&cnt[rv.x], 1);
    if (rv.y >= 0) atomicAdd(&cnt[rv.y], 1);
    if (rv.z >= 0) atomicAdd(&cnt[rv.z], 1);
    if (rv.w >= 0) atomicAdd(&cnt[rv.w], 1);
  }
  gg.sync();

  // ---------- Phase D1: per-block nonzero counts over cnt ----------
  int val[4];
  int cme;
  {
    int base = bid << 10;
    int4 cv = *(const int4*)(cnt + base + (tid << 2));
    val[0] = cv.x; val[1] = cv.y; val[2] = cv.z; val[3] = cv.w;
    cme = (cv.x > 0) + (cv.y > 0) + (cv.z > 0) + (cv.w > 0);
    int c = cme;
    for (int o = 32; o > 0; o >>= 1) c += __shfl_down(c, o);
    if (!lane) redi[wv] = c;
    __syncthreads();
    if (!tid) bcnt[bid] = redi[0] + redi[1] + redi[2] + redi[3];
  }
  gg.sync();

  // ---------- Phase D2: every block computes its prefix; scatter ----------
  {
    int4 bv = *(const int4*)(bcnt + (tid << 2));
    int j0 = tid << 2;
    int tot = bv.x + bv.y + bv.z + bv.w;
    int pre = ((j0 + 0 < bid) ? bv.x : 0) + ((j0 + 1 < bid) ? bv.y : 0)
            + ((j0 + 2 < bid) ? bv.z : 0) + ((j0 + 3 < bid) ? bv.w : 0);
    for (int o = 32; o > 0; o >>= 1) {
      tot += __shfl_down(tot, o);
      pre += __shfl_down(pre, o);
    }
    if (!lane) { redi[wv] = tot; redp4[wv] = pre; }
    __syncthreads();
    tot = redi[0] + redi[1] + redi[2] + redi[3];
    pre = redp4[0] + redp4[1] + redp4[2] + redp4[3];
    if (bid == 0 && tid == 0) sc->n_comp = tot;
    // block-local exclusive scan of cme
    int v = cme;
    for (int o = 1; o < 64; o <<= 1) {
      int u = __shfl_up(v, o);
      if (lane >= o) v += u;
    }
    if (lane == 63) wtot[wv] = v;
    __syncthreads();
    int add = 0;
    for (int w = 0; w < wv; ++w) add += wtot[w];
    int d = pre + v + add - cme;
    int base = bid << 10;
#pragma unroll
    for (int k = 0; k < 4; ++k) {
      int c = val[k];
      if (c > 0) {
        if (d < CAP) cntD[d] = c;
        cnt[base + (tid << 2) + k] = d;   // cnt becomes dense_of
        ++d;
      }
    }
  }
  gg.sync();

  // ---------- Phase E: confusion counts for all t ----------
  {
    int i0 = g << 2;
    int4 rv = *(const int4*)(P + i0);
    int4 tv = *(const int4*)(tgt + i0);
#define DO(R, T)                                                     \
    if ((R) >= 0 && (T)) {                                           \
      int dd = cnt[R];                                               \
      if ((unsigned)dd < CAP) atomicAdd(&interD[((size_t)dd << 4) + (T) - 1], 1); \
    }
    DO(rv.x, tv.x) DO(rv.y, tv.y) DO(rv.z, tv.z) DO(rv.w, tv.w)
#undef DO
  }
  gg.sync();

  // ---------- Phase F: per-(block,t) min keys ----------
  {
    int n_comp = sc->n_comp;
    if (n_comp > CAP) n_comp = CAP;
    int d = (bid << 7) + tid;          // 128 comps per block, threads 0..127 active
    int c = 0;
    if (tid < 128 && d < n_comp) c = cntD[d];
    int itv[16];
    if (c > 0) {
#pragma unroll
      for (int k = 0; k < 4; ++k) {
        int4 r = *(const int4*)(interD + ((size_t)d << 4) + (k << 2));
        itv[(k << 2) + 0] = r.x; itv[(k << 2) + 1] = r.y;
        itv[(k << 2) + 2] = r.z; itv[(k << 2) + 3] = r.w;
      }
    }
    float cp = (float)c;
#pragma unroll
    for (int t = 0; t < 16; ++t) {
      unsigned long long key = ~0ULL;
      if (c > 0) {
        float loss = pair_loss(cp, (float)itv[t], (float)sc->cnt_t[t + 1]);
        key = ((unsigned long long)__float_as_uint(loss) << 32) | (unsigned)d;
      }
      for (int o = 32; o > 0; o >>= 1) {
        unsigned long long kk = __shfl_down(key, o);
        if (kk < key) key = kk;
      }
      if (!lane) wmin[wv][t] = key;
    }
    __syncthreads();
    if (tid < 16) {
      unsigned long long m = wmin[0][tid];
      if (wmin[1][tid] < m) m = wmin[1][tid];
      if (wmin[2][tid] < m) m = wmin[2][tid];
      if (wmin[3][tid] < m) m = wmin[3][tid];
      bm[(size_t)tid * SB + bid] = m;
    }
  }
  gg.sync();

  // ---------- Phase G: block 0 sequential greedy + final ----------
  if (bid == 0) {
    if (!tid) s_nused = 0;
    __syncthreads();
    double acc = 0.0;
    int matched = 0, un = 0;
    int n_comp = sc->n_comp;

    for (int t = 1; t <= TMAX; ++t) {
      int ct = sc->cnt_t[t];
      if (ct == 0) continue;
      for (int iter = 0; iter < 64; ++iter) {
        const unsigned long long* row = bm + (size_t)(t - 1) * SB;
        unsigned long long key = row[tid];
        unsigned long long kk = row[tid + 256]; if (kk < key) key = kk;
        kk = row[tid + 512]; if (kk < key) key = kk;
        kk = row[tid + 768]; if (kk < key) key = kk;
        for (int o = 32; o > 0; o >>= 1) {
          kk = __shfl_down(key, o);
          if (kk < key) key = kk;
        }
        if (!lane) wmin[wv][0] = key;
        __syncthreads();
        if (!tid) {
          unsigned long long m = wmin[0][0];
          if (wmin[1][0] < m) m = wmin[1][0];
          if (wmin[2][0] < m) m = wmin[2][0];
          if (wmin[3][0] < m) m = wmin[3][0];
          s_m = m;
          int st = 0;
          if (m == ~0ULL) st = 2;
          else {
            int dd = (int)(m & 0xFFFFFFFFu);
            for (int u = 0; u < s_nused; ++u)
              if (s_used[u] == dd) { st = 1; break; }
          }
          s_state = st;
        }
        __syncthreads();
        int st = s_state;
        unsigned long long m = s_m;
        if (st == 0) {
          acc += (double)__uint_as_float((unsigned)(m >> 32));
          matched += 1;
          if (!tid) { s_used[s_nused] = (int)(m & 0xFFFFFFFFu); s_nused++; }
          break;
        } else if (st == 2) {
          un += 1;
          break;
        } else {
          int dd = (int)(m & 0xFFFFFFFFu);
          int b = dd >> 7;
          unsigned long long nk = ~0ULL;
          if (tid < 128) {
            int d2 = (b << 7) + tid;
            int c = (d2 < n_comp) ? cntD[d2] : 0;
            if (c > 0) {
              bool ex = false;
              for (int u = 0; u < s_nused; ++u)
                if (s_used[u] == d2) { ex = true; break; }
              if (!ex) {
                float loss = pair_loss((float)c, (float)interD[((size_t)d2 << 4) + (t - 1)], (float)ct);
                nk = ((unsigned long long)__float_as_uint(loss) << 32) | (unsigned)d2;
              }
            }
          }
          for (int o = 32; o > 0; o >>= 1) {
            unsigned long long k2 = __shfl_down(nk, o);
            if (k2 < nk) nk = k2;
          }
          if (!lane) wmin[wv][0] = nk;
          __syncthreads();
          if (!tid) {
            unsigned long long mm = wmin[0][0];
            if (wmin[1][0] < mm) mm = wmin[1][0];
            if (wmin[2][0] < mm) mm = wmin[2][0];
            if (wmin[3][0] < mm) mm = wmin[3][0];
            bm[(size_t)(t - 1) * SB + b] = mm;
          }
          __syncthreads();
        }
      }
      __syncthreads();
    }

    if (!tid) {
      double Nd = (double)NPIX;
      double res = sc->sums[0] / Nd
                 + 1.0 - (2.0 * sc->sums[2] + 1.0) / (sc->sums[1] + sc->sums[3] + 1.0);
      out[0] = (float)(res + acc + (double)(n_comp - matched) + (double)un);
    }
  }
}

// ==================== fallback path (round-4, verified) ====================
__global__ __launch_bounds__(256) void k_init(const float* __restrict__ pred,
                                              const int* __restrict__ tgt,
                                              int* __restrict__ P,
                                              int* __restrict__ cnt,
                                              double* __restrict__ part) {
  __shared__ int hist[TMAX + 1];
  __shared__ double red[4][4];
  int tid = threadIdx.x;
  if (tid <= TMAX) hist[tid] = 0;
  __syncthreads();
  int g = blockIdx.x * 256 + tid;
  int i = g << 2;
  int b = i >> 18;
  int hw = i & (HWSZ - 1);
  const float* pb = pred + ((size_t)(b << 1)) * HWSZ;
  float4 p0 = *(const float4*)(pb + hw);
  float4 p1 = *(const float4*)(pb + HWSZ + hw);
  int4 tv = *(const int4*)(tgt + i);
  int4 lv;
  float s0 = 0.f, s1 = 0.f, s2 = 0.f, s3 = 0.f;
#define ELEM(P0, P1, TV, IDX, LOUT)                              \
  {                                                              \
    bool fg = (P1) > (P0);                                       \
    float logit = fg ? (P1) : 0.0f;                              \
    float tb = ((TV) > 0) ? 1.0f : 0.0f;                         \
    float sp = fmaxf(logit, 0.0f) + log1pf(expf(-fabsf(logit))); \
    s0 += sp - logit * tb;                                       \
    float pr = 1.0f / (1.0f + expf(-logit));                     \
    s1 += pr; s2 += pr * tb; s3 += tb;                           \
    atomicAdd(&hist[TV], 1);                                     \
    LOUT = fg ? (IDX) : -1;                                      \
  }
  ELEM(p0.x, p1.x, tv.x, i + 0, lv.x)
  ELEM(p0.y, p1.y, tv.y, i + 1, lv.y)
  ELEM(p0.z, p1.z, tv.z, i + 2, lv.z)
  ELEM(p0.w, p1.w, tv.w, i + 3, lv.w)
#undef ELEM
  *(int4*)(P + i) = lv;
  *(int4*)(cnt + i) = make_int4(0, 0, 0, 0);
  for (int o = 32; o > 0; o >>= 1) {
    s0 += __shfl_down(s0, o);
    s1 += __shfl_down(s1, o);
    s2 += __shfl_down(s2, o);
    s3 += __shfl_down(s3, o);
  }
  int lane = tid & 63, wid = tid >> 6;
  if (!lane) { red[wid][0] = s0; red[wid][1] = s1; red[wid][2] = s2; red[wid][3] = s3; }
  __syncthreads();
  double* row = part + (size_t)blockIdx.x * NPART;
  if (tid <= TMAX) row[4 + tid] = (double)hist[tid];
  if (!tid) {
    row[0] = red[0][0] + red[1][0] + red[2][0] + red[3][0];
    row[1] = red[0][1] + red[1][1] + red[2][1] + red[3][1];
    row[2] = red[0][2] + red[1][2] + red[2][2] + red[3][2];
    row[3] = red[0][3] + red[1][3] + red[2][3] + red[3][3];
  }
}

__global__ __launch_bounds__(256) void k_reduce(const double* __restrict__ part,
                                                Scalars* sc) {
  double v[21];
#pragma unroll
  for (int j = 0; j < 21; ++j) v[j] = 0.0;
  for (int r = threadIdx.x; r < INIT_BLOCKS; r += 256) {
    const double* row = part + (size_t)r * NPART;
#pragma unroll
    for (int j = 0; j < 21; ++j) v[j] += row[j];
  }
#pragma unroll
  for (int o = 32; o > 0; o >>= 1) {
#pragma unroll
    for (int j = 0; j < 21; ++j) v[j] += __shfl_down(v[j], o);
  }
  __shared__ double red[4][21];
  int lane = threadIdx.x & 63, wid = threadIdx.x >> 6;
  if (!lane) {
#pragma unroll
    for (int j = 0; j < 21; ++j) red[wid][j] = v[j];
  }
  __syncthreads();
  if (!threadIdx.x) {
#pragma unroll
    for (int j = 0; j < 21; ++j) v[j] = red[0][j] + red[1][j] + red[2][j] + red[3][j];
    sc->sums[0] = v[0]; sc->sums[1] = v[1]; sc->sums[2] = v[2]; sc->sums[3] = v[3];
    for (int j = 0; j <= TMAX; ++j) sc->cnt_t[j] = (int)(v[4 + j] + 0.5);
    sc->n_comp = 0;
  }
}

__global__ __launch_bounds__(256) void k_link(int* __restrict__ P) {
  int i = blockIdx.x * 256 + threadIdx.x;
  if (P[i] < 0) return;
  int hw = i & (HWSZ - 1);
  int h = hw >> 9;
  int w = hw & (WW - 1);
  if (w < WW - 1 && P[i + 1] >= 0)  uniteF(P, i, i + 1);
  if (h < HH - 1 && P[i + WW] >= 0) uniteF(P, i, i + WW);
}

__global__ __launch_bounds__(256) void k_flatcnt(const int* __restrict__ P,
                                                 int* __restrict__ lab,
                                                 int* __restrict__ cnt,
                                                 int* __restrict__ interD) {
  int i = blockIdx.x * 256 + threadIdx.x;
  *(int2*)(interD + ((size_t)i << 1)) = make_int2(0, 0);
  int p = P[i];
  if (p < 0) { lab[i] = 0; return; }
  int r = i;
  while (p != r) { r = p; p = P[r]; }
  lab[i] = r + 1;
  atomicAdd(&cnt[r], 1);
}

__global__ __launch_bounds__(256) void k_bcnt(const int* __restrict__ cnt,
                                              int* __restrict__ bcnt) {
  int base = (blockIdx.x * 256 + threadIdx.x) << 4;
  int c = 0;
#pragma unroll
  for (int k = 0; k < 4; ++k) {
    int4 v = *(const int4*)(cnt + base + (k << 2));
    c += (v.x > 0) + (v.y > 0) + (v.z > 0) + (v.w > 0);
  }
  for (int o = 32; o > 0; o >>= 1) c += __shfl_down(c, o);
  __shared__ int red[4];
  int lane = threadIdx.x & 63, wid = threadIdx.x >> 6;
  if (!lane) red[wid] = c;
  __syncthreads();
  if (!threadIdx.x) bcnt[blockIdx.x] = red[0] + red[1] + red[2] + red[3];
}

__global__ __launch_bounds__(256) void k_scanexc(int* __restrict__ bcnt, Scalars* sc) {
  int tid = threadIdx.x;
  int lane = tid & 63, wv = tid >> 6;
  int orig = bcnt[tid];
  int v = orig;
  for (int o = 1; o < 64; o <<= 1) {
    int u = __shfl_up(v, o);
    if (lane >= o) v += u;
  }
  __shared__ int wtot[4];
  if (lane == 63) wtot[wv] = v;
  __syncthreads();
  int add = 0;
  for (int w = 0; w < wv; ++w) add += wtot[w];
  v += add;
  bcnt[tid] = v - orig;
  if (tid == 255) sc->n_comp = v;
}

__global__ __launch_bounds__(256) void k_scatter(int* __restrict__ cnt,
                                                 const int* __restrict__ bcnt,
                                                 int* __restrict__ cntD) {
  int tid = threadIdx.x;
  int base = (blockIdx.x * 256 + tid) << 4;
  int val[16];
  int cme = 0;
#pragma unroll
  for (int k = 0; k < 4; ++k) {
    int4 v = *(const int4*)(cnt + base + (k << 2));
    val[(k << 2) + 0] = v.x; val[(k << 2) + 1] = v.y;
    val[(k << 2) + 2] = v.z; val[(k << 2) + 3] = v.w;
    cme += (v.x > 0) + (v.y > 0) + (v.z > 0) + (v.w > 0);
  }
  int lane = tid & 63, wv = tid >> 6;
  int v = cme;
  for (int o = 1; o < 64; o <<= 1) {
    int u = __shfl_up(v, o);
    if (lane >= o) v += u;
  }
  __shared__ int wtot[4];
  if (lane == 63) wtot[wv] = v;
  __syncthreads();
  int add = 0;
  for (int w = 0; w < wv; ++w) add += wtot[w];
  int d = bcnt[blockIdx.x] + v + add - cme;
#pragma unroll
  for (int k = 0; k < 16; ++k) {
    int c = val[k];
    if (c > 0) {
      if (d < CAP) cntD[d] = c;
      cnt[base + k] = d;
      ++d;
    }
  }
}

__global__ __launch_bounds__(256) void k_interall(const int* __restrict__ lab,
                                                  const int* __restrict__ tgt,
                                                  const int* __restrict__ dense_of,
                                                  int* __restrict__ interD) {
  int g = blockIdx.x * 256 + threadIdx.x;
  int4 v = *(const int4*)(lab + ((size_t)g << 2));
  int4 t = *(const int4*)(tgt + ((size_t)g << 2));
#define DO(V, T)                                                   \
  if ((V) && (T)) {                                                \
    int dD = dense_of[(V) - 1];                                    \
    if ((unsigned)dD < CAP) atomicAdd(&interD[(dD << 4) + (T) - 1], 1); \
  }
  DO(v.x, t.x) DO(v.y, t.y) DO(v.z, t.z) DO(v.w, t.w)
#undef DO
}

__global__ __launch_bounds__(256) void k_scanmins(const Scalars* __restrict__ sc,
                                                  const int* __restrict__ cntD,
                                                  const int* __restrict__ interD,
                                                  unsigned long long* __restrict__ bm) {
  int tid = threadIdx.x;
  int d = blockIdx.x * 256 + tid;
  int n_comp = sc->n_comp;
  int c = (d < n_comp) ? cntD[d] : 0;
  int itv[16];
  if (c > 0) {
#pragma unroll
    for (int k = 0; k < 4; ++k) {
      int4 r = *(const int4*)(interD + ((size_t)d << 4) + (k << 2));
      itv[(k << 2) + 0] = r.x; itv[(k << 2) + 1] = r.y;
      itv[(k << 2) + 2] = r.z; itv[(k << 2) + 3] = r.w;
    }
  }
  __shared__ unsigned long long wmin[4][16];
  float cp = (float)c;
  int lane = tid & 63, wv = tid >> 6;
#pragma unroll
  for (int t = 0; t < 16; ++t) {
    unsigned long long key = ~0ULL;
    if (c > 0) {
      float loss = pair_loss(cp, (float)itv[t], (float)sc->cnt_t[t + 1]);
      key = ((unsigned long long)__float_as_uint(loss) << 32) | (unsigned)d;
    }
    for (int o = 32; o > 0; o >>= 1) {
      unsigned long long kk = __shfl_down(key, o);
      if (kk < key) key = kk;
    }
    if (!lane) wmin[wv][t] = key;
  }
  __syncthreads();
  if (tid < 16) {
    unsigned long long m = wmin[0][tid];
    if (wmin[1][tid] < m) m = wmin[1][tid];
    if (wmin[2][tid] < m) m = wmin[2][tid];
    if (wmin[3][tid] < m) m = wmin[3][tid];
    bm[(size_t)tid * SBLK + blockIdx.x] = m;
  }
}

__global__ __launch_bounds__(256) void k_greedy(const Scalars* __restrict__ sc,
                                                const int* __restrict__ cntD,
                                                const int* __restrict__ interD,
                                                unsigned long long* __restrict__ bm,
                                                float* __restrict__ out) {
  __shared__ int s_used[16];
  __shared__ int s_nused;
  __shared__ unsigned long long s_m;
  __shared__ int s_state;
  __shared__ unsigned long long wmin[4];
  int tid = threadIdx.x;
  int lane = tid & 63, wv = tid >> 6;
  if (!tid) s_nused = 0;
  __syncthreads();
  double acc = 0.0;
  int matched = 0, un = 0;
  int n_comp = sc->n_comp;
  for (int t = 1; t <= TMAX; ++t) {
    int ct = sc->cnt_t[t];
    if (ct == 0) continue;
    for (int iter = 0; iter < 64; ++iter) {
      const unsigned long long* row = bm + (size_t)(t - 1) * SBLK;
      unsigned long long k1 = row[tid];
      unsigned long long k2 = row[tid + 256];
      unsigned long long key = (k2 < k1) ? k2 : k1;
      for (int o = 32; o > 0; o >>= 1) {
        unsigned long long kk = __shfl_down(key, o);
        if (kk < key) key = kk;
      }
      if (!lane) wmin[wv] = key;
      __syncthreads();
      if (!tid) {
        unsigned long long m = wmin[0];
        if (wmin[1] < m) m = wmin[1];
        if (wmin[2] < m) m = wmin[2];
        if (wmin[3] < m) m = wmin[3];
        s_m = m;
        int st = 0;
        if (m == ~0ULL) st = 2;
        else {
          int dd = (int)(m & 0xFFFFFFFFu);
          for (int u = 0; u < s_nused; ++u)
            if (s_used[u] == dd) { st = 1; break; }
        }
        s_state = st;
      }
      __syncthreads();
      int st = s_state;
      unsigned long long m = s_m;
      if (st == 0) {
        acc += (double)__uint_as_float((unsigned)(m >> 32));
        matched += 1;
        if (!tid) { s_used[s_nused] = (int)(m & 0xFFFFFFFFu); s_nused++; }
        break;
      } else if (st == 2) {
        un += 1;
        break;
      } else {
        int dd = (int)(m & 0xFFFFFFFFu);
        int b = dd >> 8;
        int d2 = (b << 8) + tid;
        unsigned long long nk = ~0ULL;
        int c = (d2 < n_comp) ? cntD[d2] : 0;
        if (c > 0) {
          bool ex = false;
          for (int u = 0; u < s_nused; ++u)
            if (s_used[u] == d2) { ex = true; break; }
          if (!ex) {
            float loss = pair_loss((float)c, (float)interD[((size_t)d2 << 4) + (t - 1)], (float)ct);
            nk = ((unsigned long long)__float_as_uint(loss) << 32) | (unsigned)d2;
          }
        }
        for (int o = 32; o > 0; o >>= 1) {
          unsigned long long kk = __shfl_down(nk, o);
          if (kk < nk) nk = kk;
        }
        if (!lane) wmin[wv] = nk;
        __syncthreads();
        if (!tid) {
          unsigned long long mm = wmin[0];
          if (wmin[1] < mm) mm = wmin[1];
          if (wmin[2] < mm) mm = wmin[2];
          if (wmin[3] < mm) mm = wmin[3];
          bm[(size_t)(t - 1) * SBLK + b] = mm;
        }
        __syncthreads();
      }
    }
    __syncthreads();
  }
  if (!tid) {
    double Nd = (double)NPIX;
    double res = sc->sums[0] / Nd
               + 1.0 - (2.0 * sc->sums[2] + 1.0) / (sc->sums[1] + sc->sums[3] + 1.0);
    out[0] = (float)(res + acc + (double)(n_comp - matched) + (double)un);
  }
}

extern "C" void kernel_launch(void* const* d_in, const int* in_sizes, int n_in,
                              void* d_out, int out_size, void* d_ws, size_t ws_size,
                              hipStream_t stream) {
  (void)in_sizes; (void)n_in; (void)out_size; (void)ws_size;
  const float* pred = (const float*)d_in[0];
  const int* tgt = (const int*)d_in[1];
  float* out = (float*)d_out;

  char* w = (char*)d_ws;
  int* P     = (int*)w;            w += (size_t)NPIX * 4;
  int* lab   = (int*)w;            w += (size_t)NPIX * 4;     // fallback only
  int* cnt   = (int*)w;            w += (size_t)NPIX * 4;
  double* part = (double*)w;       w += (size_t)MB * NPART * 8;
  Scalars* sc = (Scalars*)w;       w += 256;
  int* bcnt  = (int*)w;            w += 4096;                 // 1024 ints
  int* cntD  = (int*)w;            w += (size_t)CAP * 4;
  unsigned long long* bm = (unsigned long long*)w; w += (size_t)16 * SB * 8;
  int* interD = (int*)w;           // CAP * 16 * 4 = 8 MB

  void* args[] = { (void*)&pred, (void*)&tgt, (void*)&P, (void*)&cnt, (void*)&part,
                   (void*)&sc, (void*)&bcnt, (void*)&cntD, (void*)&interD,
                   (void*)&bm, (void*)&out };
  hipError_t e = hipLaunchCooperativeKernel((const void*)k_mega, dim3(MB), dim3(256),
                                            args, 0, stream);
  if (e == hipSuccess) return;

  // ---- fallback: round-4 verified 10-kernel path ----
  k_init<<<INIT_BLOCKS, 256, 0, stream>>>(pred, tgt, P, cnt, part);
  k_reduce<<<1, 256, 0, stream>>>(part, sc);
  k_link<<<NPIX / 256, 256, 0, stream>>>(P);
  k_flatcnt<<<NPIX / 256, 256, 0, stream>>>(P, lab, cnt, interD);
  k_bcnt<<<CBLK, 256, 0, stream>>>(cnt, bcnt);
  k_scanexc<<<1, 256, 0, stream>>>(bcnt, sc);
  k_scatter<<<CBLK, 256, 0, stream>>>(cnt, bcnt, cntD);
  k_interall<<<NPIX / 1024, 256, 0, stream>>>(lab, tgt, cnt, interD);
  k_scanmins<<<SBLK, 256, 0, stream>>>(sc, cntD, interD, bm);
  k_greedy<<<1, 256, 0, stream>>>(sc, cntD, interD, bm, out);
}

// Round 6
// 145.873 us; speedup vs baseline: 6.4594x; 6.4594x over previous
//
#include <hip/hip_runtime.h>
#include <math.h>

#define HH 512
#define WW 512
#define HWSZ (HH * WW)          // 262144
#define NB 4
#define NPIX (NB * HWSZ)        // 1048576
#define TMAX 16

#define CAP 131072              // dense component capacity (observed n_comp ~70k)
#define NPART 24                // padded partials row (21 used)
#define NBLK 1024               // standard pixel-pass blocks (4 px/thread)
#define SBLK 512                // scanmins blocks; each covers 256 dense comps

struct Scalars {
  double sums[4];               // bce, sum_p, sum_pt, sum_t
  int cnt_t[TMAX + 1];
  int n_comp;
};

__device__ __forceinline__ float pair_loss(float cp, float it, float ctf) {
  const float Nf = (float)NPIX;
  float bce = (Nf * 0.69314718f + cp * 0.62011451f - it) / Nf;  // SP0, SP1-SP0
  float sum_pt = 0.5f * ctf + 0.23105858f * it;                 // S1-0.5
  float sum_p = 0.5f * Nf + 0.23105858f * cp;
  float dice = 1.0f - (2.0f * sum_pt + 1.0f) / (sum_p + ctf + 1.0f);
  return bce + dice;            // always > 0 -> float bits order == value order
}

// ---- union-find (max-root) with path-halving (HW-verified in r5 mega) ----
__device__ __forceinline__ int chaseRO(const int* __restrict__ P, int x) {
  int p = P[x];
  while (p != x) { x = p; p = P[x]; }
  return x;
}
__device__ __forceinline__ int findRootH(int* P, int x) {
  int p = P[x];
  while (p != x) {
    int gp = P[p];
    if (gp == p) return p;
    P[x] = gp;                   // halving: writes a valid ancestor, monotone
    x = gp; p = P[x];
  }
  return x;
}
__device__ void unite(int* P, int a, int b) {
  a = findRootH(P, a);
  b = findRootH(P, b);
  for (;;) {
    if (a == b) return;
    if (a > b) { int t = a; a = b; b = t; }     // a < b : link a -> b
    int old = atomicMax(&P[a], b);
    if (old == a) return;
    a = findRootH(P, old);
    b = findRootH(P, b);
  }
}

// ---- k_init: fg mask, parents, cnt=0, base-loss partials, target hist ----
__global__ __launch_bounds__(256) void k_init(const float* __restrict__ pred,
                                              const int* __restrict__ tgt,
                                              int* __restrict__ P,
                                              int* __restrict__ cnt,
                                              double* __restrict__ part) {
  __shared__ int hist[TMAX + 1];
  __shared__ double red[4][4];
  int tid = threadIdx.x;
  if (tid <= TMAX) hist[tid] = 0;
  __syncthreads();
  int g = blockIdx.x * 256 + tid;
  int i = g << 2;
  int b = i >> 18;
  int hw = i & (HWSZ - 1);
  const float* pb = pred + ((size_t)(b << 1)) * HWSZ;
  float4 p0 = *(const float4*)(pb + hw);
  float4 p1 = *(const float4*)(pb + HWSZ + hw);
  int4 tv = *(const int4*)(tgt + i);
  int4 lv;
  float s0 = 0.f, s1 = 0.f, s2 = 0.f, s3 = 0.f;
#define ELEM(P0, P1, TV, IDX, LOUT)                              \
  {                                                              \
    bool fg = (P1) > (P0);                                       \
    float logit = fg ? (P1) : 0.0f;                              \
    float tb = ((TV) > 0) ? 1.0f : 0.0f;                         \
    float sp = fmaxf(logit, 0.0f) + log1pf(expf(-fabsf(logit))); \
    s0 += sp - logit * tb;                                       \
    float pr = 1.0f / (1.0f + expf(-logit));                     \
    s1 += pr; s2 += pr * tb; s3 += tb;                           \
    atomicAdd(&hist[TV], 1);                                     \
    LOUT = fg ? (IDX) : -1;                                      \
  }
  ELEM(p0.x, p1.x, tv.x, i + 0, lv.x)
  ELEM(p0.y, p1.y, tv.y, i + 1, lv.y)
  ELEM(p0.z, p1.z, tv.z, i + 2, lv.z)
  ELEM(p0.w, p1.w, tv.w, i + 3, lv.w)
#undef ELEM
  *(int4*)(P + i) = lv;
  *(int4*)(cnt + i) = make_int4(0, 0, 0, 0);
  for (int o = 32; o > 0; o >>= 1) {
    s0 += __shfl_down(s0, o);
    s1 += __shfl_down(s1, o);
    s2 += __shfl_down(s2, o);
    s3 += __shfl_down(s3, o);
  }
  int lane = tid & 63, wid = tid >> 6;
  if (!lane) { red[wid][0] = s0; red[wid][1] = s1; red[wid][2] = s2; red[wid][3] = s3; }
  __syncthreads();
  double* row = part + (size_t)blockIdx.x * NPART;
  if (tid <= TMAX) row[4 + tid] = (double)hist[tid];
  if (!tid) {
    row[0] = red[0][0] + red[1][0] + red[2][0] + red[3][0];
    row[1] = red[0][1] + red[1][1] + red[2][1] + red[3][1];
    row[2] = red[0][2] + red[1][2] + red[2][2] + red[3][2];
    row[3] = red[0][3] + red[1][3] + red[2][3] + red[3][3];
  }
}

// ---- k_linkred: block 0 reduces partials -> sc; all blocks link (4 px/thread) ----
__global__ __launch_bounds__(256) void k_linkred(int* __restrict__ P,
                                                 const double* __restrict__ part,
                                                 Scalars* __restrict__ sc) {
  int tid = threadIdx.x;
  int bid = blockIdx.x;
  int lane = tid & 63, wv = tid >> 6;
  if (bid == 0) {
    double v[21];
#pragma unroll
    for (int j = 0; j < 21; ++j) v[j] = 0.0;
    for (int r = tid; r < NBLK; r += 256) {
      const double* row = part + (size_t)r * NPART;
#pragma unroll
      for (int j = 0; j < 21; ++j) v[j] += row[j];
    }
#pragma unroll
    for (int o = 32; o > 0; o >>= 1) {
#pragma unroll
      for (int j = 0; j < 21; ++j) v[j] += __shfl_down(v[j], o);
    }
    __shared__ double redr[4][21];
    if (!lane) {
#pragma unroll
      for (int j = 0; j < 21; ++j) redr[wv][j] = v[j];
    }
    __syncthreads();
    if (!tid) {
#pragma unroll
      for (int j = 0; j < 21; ++j) v[j] = redr[0][j] + redr[1][j] + redr[2][j] + redr[3][j];
      sc->sums[0] = v[0]; sc->sums[1] = v[1]; sc->sums[2] = v[2]; sc->sums[3] = v[3];
      for (int j = 0; j <= TMAX; ++j) sc->cnt_t[j] = (int)(v[4 + j] + 0.5);
    }
  }
  int base = bid << 10;
#pragma unroll
  for (int k = 0; k < 4; ++k) {
    int i = base + (k << 8) + tid;
    if (P[i] >= 0) {
      int hw = i & (HWSZ - 1);
      int h = hw >> 9;
      int w = hw & (WW - 1);
      if (w < WW - 1 && P[i + 1] >= 0)  unite(P, i, i + 1);
      if (h < HH - 1 && P[i + WW] >= 0) unite(P, i, i + WW);
    }
  }
}

// ---- k_flat: in-place flatten P to roots + per-root counts + zero interD ----
__global__ __launch_bounds__(256) void k_flat(int* __restrict__ P,
                                              int* __restrict__ cnt,
                                              int* __restrict__ interD) {
  int g = blockIdx.x * 256 + threadIdx.x;
  // zero interD: 8 ints/thread covers CAP*16 = 2M ints
  *(int4*)(interD + ((size_t)g << 3)) = make_int4(0, 0, 0, 0);
  *(int4*)(interD + ((size_t)g << 3) + 4) = make_int4(0, 0, 0, 0);
  int i0 = g << 2;
  int4 pv = *(const int4*)(P + i0);
  int4 rv;
  rv.x = (pv.x < 0) ? -1 : chaseRO(P, pv.x);
  rv.y = (pv.y < 0) ? -1 : chaseRO(P, pv.y);
  rv.z = (pv.z < 0) ? -1 : chaseRO(P, pv.z);
  rv.w = (pv.w < 0) ? -1 : chaseRO(P, pv.w);
  *(int4*)(P + i0) = rv;        // owner-exclusive store; chase through flattened
  if (rv.x >= 0) atomicAdd(&cnt[rv.x], 1);
  if (rv.y >= 0) atomicAdd(&cnt[rv.y], 1);
  if (rv.z >= 0) atomicAdd(&cnt[rv.z], 1);
  if (rv.w >= 0) atomicAdd(&cnt[rv.w], 1);
}

// ---- k_bcnt: per-block nonzero counts over cnt (1024 ints/block) ----
__global__ __launch_bounds__(256) void k_bcnt(const int* __restrict__ cnt,
                                              int* __restrict__ bcnt) {
  __shared__ int redi[4];
  int tid = threadIdx.x;
  int base = blockIdx.x << 10;
  int4 cv = *(const int4*)(cnt + base + (tid << 2));
  int c = (cv.x > 0) + (cv.y > 0) + (cv.z > 0) + (cv.w > 0);
  for (int o = 32; o > 0; o >>= 1) c += __shfl_down(c, o);
  int lane = tid & 63, wv = tid >> 6;
  if (!lane) redi[wv] = c;
  __syncthreads();
  if (!tid) bcnt[blockIdx.x] = redi[0] + redi[1] + redi[2] + redi[3];
}

// ---- k_scatter: inline global prefix from bcnt + block scan + scatter ----
__global__ __launch_bounds__(256) void k_scatter(int* __restrict__ cnt,
                                                 const int* __restrict__ bcnt,
                                                 int* __restrict__ cntD,
                                                 Scalars* __restrict__ sc) {
  __shared__ int redi[4];
  __shared__ int redp4[4];
  __shared__ int wtot[4];
  int tid = threadIdx.x;
  int bid = blockIdx.x;
  int lane = tid & 63, wv = tid >> 6;
  int base = bid << 10;
  int4 cv = *(const int4*)(cnt + base + (tid << 2));
  int val[4] = { cv.x, cv.y, cv.z, cv.w };
  int cme = (cv.x > 0) + (cv.y > 0) + (cv.z > 0) + (cv.w > 0);
  // global prefix: sum of bcnt[j] for j < bid (and total for n_comp)
  int4 bv = *(const int4*)(bcnt + (tid << 2));
  int j0 = tid << 2;
  int tot = bv.x + bv.y + bv.z + bv.w;
  int pre = ((j0 + 0 < bid) ? bv.x : 0) + ((j0 + 1 < bid) ? bv.y : 0)
          + ((j0 + 2 < bid) ? bv.z : 0) + ((j0 + 3 < bid) ? bv.w : 0);
  for (int o = 32; o > 0; o >>= 1) {
    tot += __shfl_down(tot, o);
    pre += __shfl_down(pre, o);
  }
  if (!lane) { redi[wv] = tot; redp4[wv] = pre; }
  __syncthreads();
  tot = redi[0] + redi[1] + redi[2] + redi[3];
  pre = redp4[0] + redp4[1] + redp4[2] + redp4[3];
  if (bid == 0 && tid == 0) sc->n_comp = tot;
  // block-local exclusive scan of cme
  int v = cme;
  for (int o = 1; o < 64; o <<= 1) {
    int u = __shfl_up(v, o);
    if (lane >= o) v += u;
  }
  if (lane == 63) wtot[wv] = v;
  __syncthreads();
  int add = 0;
  for (int w = 0; w < wv; ++w) add += wtot[w];
  int d = pre + v + add - cme;
#pragma unroll
  for (int k = 0; k < 4; ++k) {
    int c = val[k];
    if (c > 0) {
      if (d < CAP) cntD[d] = c;
      cnt[base + (tid << 2) + k] = d;     // cnt becomes dense_of
      ++d;
    }
  }
}

// ---- k_interall: confusion counts for all t in one pass (P holds roots) ----
__global__ __launch_bounds__(256) void k_interall(const int* __restrict__ P,
                                                  const int* __restrict__ tgt,
                                                  const int* __restrict__ dense_of,
                                                  int* __restrict__ interD) {
  int g = blockIdx.x * 256 + threadIdx.x;
  int i0 = g << 2;
  int4 rv = *(const int4*)(P + i0);
  int4 tv = *(const int4*)(tgt + i0);
#define DO(R, T)                                                     \
  if ((R) >= 0 && (T)) {                                             \
    int dd = dense_of[R];                                            \
    if ((unsigned)dd < CAP) atomicAdd(&interD[((size_t)dd << 4) + (T) - 1], 1); \
  }
  DO(rv.x, tv.x) DO(rv.y, tv.y) DO(rv.z, tv.z) DO(rv.w, tv.w)
#undef DO
}

// ---- k_scanmins: per-(block,t) min keys (loss_bits<<32 | dense) ----
__global__ __launch_bounds__(256) void k_scanmins(const Scalars* __restrict__ sc,
                                                  const int* __restrict__ cntD,
                                                  const int* __restrict__ interD,
                                                  unsigned long long* __restrict__ bm) {
  int tid = threadIdx.x;
  int d = blockIdx.x * 256 + tid;
  int n_comp = sc->n_comp;
  int c = (d < n_comp) ? cntD[d] : 0;
  int itv[16];
  if (c > 0) {
#pragma unroll
    for (int k = 0; k < 4; ++k) {
      int4 r = *(const int4*)(interD + ((size_t)d << 4) + (k << 2));
      itv[(k << 2) + 0] = r.x; itv[(k << 2) + 1] = r.y;
      itv[(k << 2) + 2] = r.z; itv[(k << 2) + 3] = r.w;
    }
  }
  __shared__ unsigned long long wmin[4][16];
  float cp = (float)c;
  int lane = tid & 63, wv = tid >> 6;
#pragma unroll
  for (int t = 0; t < 16; ++t) {
    unsigned long long key = ~0ULL;
    if (c > 0) {
      float loss = pair_loss(cp, (float)itv[t], (float)sc->cnt_t[t + 1]);
      key = ((unsigned long long)__float_as_uint(loss) << 32) | (unsigned)d;
    }
    for (int o = 32; o > 0; o >>= 1) {
      unsigned long long kk = __shfl_down(key, o);
      if (kk < key) key = kk;
    }
    if (!lane) wmin[wv][t] = key;
  }
  __syncthreads();
  if (tid < 16) {
    unsigned long long m = wmin[0][tid];
    if (wmin[1][tid] < m) m = wmin[1][tid];
    if (wmin[2][tid] < m) m = wmin[2][tid];
    if (wmin[3][tid] < m) m = wmin[3][tid];
    bm[(size_t)tid * SBLK + blockIdx.x] = m;
  }
}

// ---- k_greedy: single-block sequential greedy + final assembly ----
__global__ __launch_bounds__(256) void k_greedy(const Scalars* __restrict__ sc,
                                                const int* __restrict__ cntD,
                                                const int* __restrict__ interD,
                                                unsigned long long* __restrict__ bm,
                                                float* __restrict__ out) {
  __shared__ int s_used[16];
  __shared__ int s_nused;
  __shared__ unsigned long long s_m;
  __shared__ int s_state;
  __shared__ unsigned long long wmin[4];
  int tid = threadIdx.x;
  int lane = tid & 63, wv = tid >> 6;
  if (!tid) s_nused = 0;
  __syncthreads();
  double acc = 0.0;
  int matched = 0, un = 0;
  int n_comp = sc->n_comp;
  for (int t = 1; t <= TMAX; ++t) {
    int ct = sc->cnt_t[t];
    if (ct == 0) continue;
    for (int iter = 0; iter < 64; ++iter) {
      const unsigned long long* row = bm + (size_t)(t - 1) * SBLK;
      unsigned long long k1 = row[tid];
      unsigned long long k2 = row[tid + 256];
      unsigned long long key = (k2 < k1) ? k2 : k1;
      for (int o = 32; o > 0; o >>= 1) {
        unsigned long long kk = __shfl_down(key, o);
        if (kk < key) key = kk;
      }
      if (!lane) wmin[wv] = key;
      __syncthreads();
      if (!tid) {
        unsigned long long m = wmin[0];
        if (wmin[1] < m) m = wmin[1];
        if (wmin[2] < m) m = wmin[2];
        if (wmin[3] < m) m = wmin[3];
        s_m = m;
        int st = 0;
        if (m == ~0ULL) st = 2;
        else {
          int dd = (int)(m & 0xFFFFFFFFu);
          for (int u = 0; u < s_nused; ++u)
            if (s_used[u] == dd) { st = 1; break; }
        }
        s_state = st;
      }
      __syncthreads();
      int st = s_state;
      unsigned long long m = s_m;
      if (st == 0) {
        acc += (double)__uint_as_float((unsigned)(m >> 32));
        matched += 1;
        if (!tid) { s_used[s_nused] = (int)(m & 0xFFFFFFFFu); s_nused++; }
        break;
      } else if (st == 2) {
        un += 1;
        break;
      } else {
        int dd = (int)(m & 0xFFFFFFFFu);
        int b = dd >> 8;
        int d2 = (b << 8) + tid;
        unsigned long long nk = ~0ULL;
        int c = (d2 < n_comp) ? cntD[d2] : 0;
        if (c > 0) {
          bool ex = false;
          for (int u = 0; u < s_nused; ++u)
            if (s_used[u] == d2) { ex = true; break; }
          if (!ex) {
            float loss = pair_loss((float)c, (float)interD[((size_t)d2 << 4) + (t - 1)], (float)ct);
            nk = ((unsigned long long)__float_as_uint(loss) << 32) | (unsigned)d2;
          }
        }
        for (int o = 32; o > 0; o >>= 1) {
          unsigned long long kk = __shfl_down(nk, o);
          if (kk < nk) nk = kk;
        }
        if (!lane) wmin[wv] = nk;
        __syncthreads();
        if (!tid) {
          unsigned long long mm = wmin[0];
          if (wmin[1] < mm) mm = wmin[1];
          if (wmin[2] < mm) mm = wmin[2];
          if (wmin[3] < mm) mm = wmin[3];
          bm[(size_t)(t - 1) * SBLK + b] = mm;
        }
        __syncthreads();
      }
    }
    __syncthreads();
  }
  if (!tid) {
    double Nd = (double)NPIX;
    double res = sc->sums[0] / Nd
               + 1.0 - (2.0 * sc->sums[2] + 1.0) / (sc->sums[1] + sc->sums[3] + 1.0);
    out[0] = (float)(res + acc + (double)(n_comp - matched) + (double)un);
  }
}

extern "C" void kernel_launch(void* const* d_in, const int* in_sizes, int n_in,
                              void* d_out, int out_size, void* d_ws, size_t ws_size,
                              hipStream_t stream) {
  (void)in_sizes; (void)n_in; (void)out_size; (void)ws_size;
  const float* pred = (const float*)d_in[0];
  const int* tgt = (const int*)d_in[1];
  float* out = (float*)d_out;

  char* w = (char*)d_ws;
  int* P     = (int*)w;            w += (size_t)NPIX * 4;     // parents -> roots
  int* cnt   = (int*)w;            w += (size_t)NPIX * 4;     // counts -> dense_of
  double* part = (double*)w;       w += (size_t)NBLK * NPART * 8;
  Scalars* sc = (Scalars*)w;       w += 256;
  int* bcnt  = (int*)w;            w += 4096;                 // 1024 ints
  int* cntD  = (int*)w;            w += (size_t)CAP * 4;
  unsigned long long* bm = (unsigned long long*)w; w += (size_t)16 * SBLK * 8;
  int* interD = (int*)w;           // CAP * 16 * 4 = 8 MB

  k_init<<<NBLK, 256, 0, stream>>>(pred, tgt, P, cnt, part);
  k_linkred<<<NBLK, 256, 0, stream>>>(P, part, sc);
  k_flat<<<NBLK, 256, 0, stream>>>(P, cnt, interD);
  k_bcnt<<<NBLK, 256, 0, stream>>>(cnt, bcnt);
  k_scatter<<<NBLK, 256, 0, stream>>>(cnt, bcnt, cntD, sc);
  k_interall<<<NBLK, 256, 0, stream>>>(P, tgt, cnt, interD);
  k_scanmins<<<SBLK, 256, 0, stream>>>(sc, cntD, interD, bm);
  k_greedy<<<1, 256, 0, stream>>>(sc, cntD, interD, bm, out);
}